// Round 1
// baseline (1909.760 us; speedup 1.0000x reference)
//
#include <hip/hip_runtime.h>
#include <cmath>
#include <algorithm>

#define NLEVELS 16

struct LevelMeta {
  float scale;       // f32(BASE_RES * GROWTH^l - 1.0)
  unsigned stride;   // res+1 (dense levels)
  unsigned offset;   // entry offset into table
  unsigned mask;     // params-1 (hashed levels; params == 2^22)
  int hashed;
};
struct MetaPack { LevelMeta m[NLEVELS]; };

// One thread per point. h[64] in registers (levels fully unrolled -> static
// indices). MLP weight rows are wave-uniform loads (scalarized to s_load).
// Layer outputs staged through LDS in [neuron][thread] layout: per-lane index
// is the fast dim -> stride-1, conflict-free, and no barrier needed (each
// thread touches only its own column).
__global__ __launch_bounds__(128, 2) void sdf_fused_kernel(
    const float* __restrict__ x,
    const float* __restrict__ table,
    const float* __restrict__ W0,
    const float* __restrict__ W1,
    const float* __restrict__ W2,
    float* __restrict__ out,
    MetaPack mp, int N)
{
  __shared__ float Hs[64 * 128];   // 32 KB -> 5 blocks/CU by LDS
  const int t = threadIdx.x;
  const int p = blockIdx.x * 128 + t;
  if (p >= N) return;

  const float px = x[3 * p + 0];
  const float py = x[3 * p + 1];
  const float pz = x[3 * p + 2];

  float h[64];

  #pragma unroll
  for (int l = 0; l < NLEVELS; ++l) {
    const float    scale  = mp.m[l].scale;
    const unsigned stride = mp.m[l].stride;
    const unsigned offset = mp.m[l].offset;
    const unsigned mask   = mp.m[l].mask;
    const int      hashed = mp.m[l].hashed;

    const float posx = px * scale + 0.5f;
    const float posy = py * scale + 0.5f;
    const float posz = pz * scale + 0.5f;
    const float flx = floorf(posx), fly = floorf(posy), flz = floorf(posz);
    const float fx = posx - flx, fy = posy - fly, fz = posz - flz;
    const unsigned bx = (unsigned)flx, by = (unsigned)fly, bz = (unsigned)flz;

    unsigned idx[8];
    if (hashed) {
      #pragma unroll
      for (int c = 0; c < 8; ++c) {
        const unsigned cx = bx + (c & 1);
        const unsigned cy = by + ((c >> 1) & 1);
        const unsigned cz = bz + ((c >> 2) & 1);
        idx[c] = ((cx ^ (cy * 2654435761u) ^ (cz * 805459861u)) & mask) + offset;
      }
    } else {
      #pragma unroll
      for (int c = 0; c < 8; ++c) {
        const unsigned cx = bx + (c & 1);
        const unsigned cy = by + ((c >> 1) & 1);
        const unsigned cz = bz + ((c >> 2) & 1);
        idx[c] = cx + cy * stride + cz * stride * stride + offset;
      }
    }

    float4 f[8];
    #pragma unroll
    for (int c = 0; c < 8; ++c)
      f[c] = ((const float4*)table)[idx[c]];

    const float wx0 = 1.0f - fx, wx1 = fx;
    const float wy0 = 1.0f - fy, wy1 = fy;
    const float wz0 = 1.0f - fz, wz1 = fz;

    float a0 = 0.f, a1 = 0.f, a2 = 0.f, a3 = 0.f;
    #pragma unroll
    for (int c = 0; c < 8; ++c) {
      const float w = ((c & 1) ? wx1 : wx0) *
                      ((c & 2) ? wy1 : wy0) *
                      ((c & 4) ? wz1 : wz0);
      a0 += w * f[c].x;
      a1 += w * f[c].y;
      a2 += w * f[c].z;
      a3 += w * f[c].w;
    }
    h[4 * l + 0] = a0;
    h[4 * l + 1] = a1;
    h[4 * l + 2] = a2;
    h[4 * l + 3] = a3;
  }

  // ---- Layer 0: h1 = relu(h @ W0^T) ----
  #pragma unroll 2
  for (int j = 0; j < 64; ++j) {
    const float* __restrict__ wr = W0 + j * 64;  // wave-uniform row -> s_load
    float a0 = 0.f, a1 = 0.f, a2 = 0.f, a3 = 0.f;
    #pragma unroll
    for (int k = 0; k < 64; k += 4) {
      a0 += wr[k + 0] * h[k + 0];
      a1 += wr[k + 1] * h[k + 1];
      a2 += wr[k + 2] * h[k + 2];
      a3 += wr[k + 3] * h[k + 3];
    }
    Hs[j * 128 + t] = fmaxf((a0 + a1) + (a2 + a3), 0.f);
  }
  #pragma unroll
  for (int k = 0; k < 64; ++k) h[k] = Hs[k * 128 + t];

  // ---- Layer 1: h2 = relu(h1 @ W1^T) ----
  #pragma unroll 2
  for (int j = 0; j < 64; ++j) {
    const float* __restrict__ wr = W1 + j * 64;
    float a0 = 0.f, a1 = 0.f, a2 = 0.f, a3 = 0.f;
    #pragma unroll
    for (int k = 0; k < 64; k += 4) {
      a0 += wr[k + 0] * h[k + 0];
      a1 += wr[k + 1] * h[k + 1];
      a2 += wr[k + 2] * h[k + 2];
      a3 += wr[k + 3] * h[k + 3];
    }
    Hs[j * 128 + t] = fmaxf((a0 + a1) + (a2 + a3), 0.f);
  }
  #pragma unroll
  for (int k = 0; k < 64; ++k) h[k] = Hs[k * 128 + t];

  // ---- Layer 2: out = h2 @ W2^T ----
  {
    float a0 = 0.f, a1 = 0.f, a2 = 0.f, a3 = 0.f;
    #pragma unroll
    for (int k = 0; k < 64; k += 4) {
      a0 += W2[k + 0] * h[k + 0];
      a1 += W2[k + 1] * h[k + 1];
      a2 += W2[k + 2] * h[k + 2];
      a3 += W2[k + 3] * h[k + 3];
    }
    out[p] = (a0 + a1) + (a2 + a3);
  }
}

extern "C" void kernel_launch(void* const* d_in, const int* in_sizes, int n_in,
                              void* d_out, int out_size, void* d_ws, size_t ws_size,
                              hipStream_t stream)
{
  const float* x  = (const float*)d_in[0];
  const float* tb = (const float*)d_in[1];
  const float* W0 = (const float*)d_in[2];
  const float* W1 = (const float*)d_in[3];
  const float* W2 = (const float*)d_in[4];
  float* out = (float*)d_out;
  const int N = out_size;  // output is (N, 1)

  // Replicate the reference's level metadata in double precision.
  MetaPack mp;
  const double growth = std::exp((std::log(2048.0) - std::log(16.0)) / 15.0);
  unsigned long long offset = 0;
  for (int l = 0; l < NLEVELS; ++l) {
    const double scale = 16.0 * std::pow(growth, (double)l) - 1.0;
    const int res = (int)std::ceil(scale) + 1;
    const long long cube = (long long)(res + 1) * (res + 1) * (res + 1);
    long long params = std::min((long long)(1 << 22), cube);
    params = ((params + 7) / 8) * 8;
    const bool dense = (cube <= params);
    mp.m[l].scale  = (float)scale;
    mp.m[l].stride = (unsigned)(res + 1);
    mp.m[l].offset = (unsigned)offset;
    mp.m[l].mask   = (unsigned)(params - 1);
    mp.m[l].hashed = dense ? 0 : 1;
    offset += (unsigned long long)params;
  }

  const int grid = (N + 127) / 128;
  hipLaunchKernelGGL(sdf_fused_kernel, dim3(grid), dim3(128), 0, stream,
                     x, tb, W0, W1, W2, out, mp, N);
}